// Round 1
// baseline (91.688 us; speedup 1.0000x reference)
//
#include <hip/hip_runtime.h>

// InvertAffine: per sample, trf (12 floats) -> rows of a 3x4 "shift" matrix.
// full = [[A+I, t],[0,1]]; inv(full) = [[Minv, -Minv*t],[0,1]] with M = A+I.
// out = [Minv - I | -Minv*t] flattened (12 floats).

__global__ __launch_bounds__(256) void invert_affine_kernel(
    const float4* __restrict__ in, float4* __restrict__ out, int B) {
  const int stride = gridDim.x * blockDim.x;
  for (int i = blockIdx.x * blockDim.x + threadIdx.x; i < B; i += stride) {
    // Row-major (3,4): r0=(m00,m01,m02,t0), r1=(m10,m11,m12,t1), r2=(m20,m21,m22,t2)
    const float4 r0 = in[3 * i + 0];
    const float4 r1 = in[3 * i + 1];
    const float4 r2 = in[3 * i + 2];

    const float a00 = r0.x + 1.0f, a01 = r0.y,        a02 = r0.z,        t0 = r0.w;
    const float a10 = r1.x,        a11 = r1.y + 1.0f, a12 = r1.z,        t1 = r1.w;
    const float a20 = r2.x,        a21 = r2.y,        a22 = r2.z + 1.0f, t2 = r2.w;

    // Cofactors of column 0 (also first column of adjugate rows)
    const float c00 = a11 * a22 - a12 * a21;
    const float c01 = a12 * a20 - a10 * a22;
    const float c02 = a10 * a21 - a11 * a20;

    const float det  = a00 * c00 + a01 * c01 + a02 * c02;
    const float rdet = 1.0f / det;

    const float i00 = c00 * rdet;
    const float i01 = (a02 * a21 - a01 * a22) * rdet;
    const float i02 = (a01 * a12 - a02 * a11) * rdet;
    const float i10 = c01 * rdet;
    const float i11 = (a00 * a22 - a02 * a20) * rdet;
    const float i12 = (a02 * a10 - a00 * a12) * rdet;
    const float i20 = c02 * rdet;
    const float i21 = (a01 * a20 - a00 * a21) * rdet;
    const float i22 = (a00 * a11 - a01 * a10) * rdet;

    const float4 o0 = make_float4(i00 - 1.0f, i01, i02,
                                  -(i00 * t0 + i01 * t1 + i02 * t2));
    const float4 o1 = make_float4(i10, i11 - 1.0f, i12,
                                  -(i10 * t0 + i11 * t1 + i12 * t2));
    const float4 o2 = make_float4(i20, i21, i22 - 1.0f,
                                  -(i20 * t0 + i21 * t1 + i22 * t2));

    out[3 * i + 0] = o0;
    out[3 * i + 1] = o1;
    out[3 * i + 2] = o2;
  }
}

extern "C" void kernel_launch(void* const* d_in, const int* in_sizes, int n_in,
                              void* d_out, int out_size, void* d_ws, size_t ws_size,
                              hipStream_t stream) {
  (void)n_in; (void)d_ws; (void)ws_size; (void)out_size;
  const float4* in4 = (const float4*)d_in[0];
  float4* out4 = (float4*)d_out;
  const int B = in_sizes[0] / 12;  // samples

  const int block = 256;
  int blocks = (B + block - 1) / block;
  if (blocks > 2048) blocks = 2048;  // grid-stride the rest (Guideline 11)

  invert_affine_kernel<<<blocks, block, 0, stream>>>(in4, out4, B);
}

// Round 2
// 79.800 us; speedup vs baseline: 1.1490x; 1.1490x over previous
//
#include <hip/hip_runtime.h>

// InvertAffine: per sample, trf (12 floats) -> rows of a 3x4 "shift" matrix.
// full = [[A+I, t],[0,1]]; inv(full) = [[Minv, -Minv*t],[0,1]] with M = A+I.
// out = [Minv - I | -Minv*t] flattened (12 floats).
//
// Global access is staged through LDS so every global load/store instruction
// is lane-contiguous float4 (16 B/lane). LDS uses PAD=13 dwords/sample: odd
// stride => 13*t mod 32 hits each bank exactly twice across 64 lanes (2-way
// aliasing is free on CDNA4).

#define PAD 13
#define TILE 256  // samples per block tile == blockDim.x

__device__ __forceinline__ void invert12(const float* __restrict__ p,
                                         float* __restrict__ q) {
  const float a00 = p[0] + 1.0f, a01 = p[1],        a02 = p[2],         t0 = p[3];
  const float a10 = p[4],        a11 = p[5] + 1.0f, a12 = p[6],         t1 = p[7];
  const float a20 = p[8],        a21 = p[9],        a22 = p[10] + 1.0f, t2 = p[11];

  const float c00 = a11 * a22 - a12 * a21;
  const float c01 = a12 * a20 - a10 * a22;
  const float c02 = a10 * a21 - a11 * a20;

  const float det  = a00 * c00 + a01 * c01 + a02 * c02;
  const float rdet = 1.0f / det;

  const float i00 = c00 * rdet;
  const float i01 = (a02 * a21 - a01 * a22) * rdet;
  const float i02 = (a01 * a12 - a02 * a11) * rdet;
  const float i10 = c01 * rdet;
  const float i11 = (a00 * a22 - a02 * a20) * rdet;
  const float i12 = (a02 * a10 - a00 * a12) * rdet;
  const float i20 = c02 * rdet;
  const float i21 = (a01 * a20 - a00 * a21) * rdet;
  const float i22 = (a00 * a11 - a01 * a10) * rdet;

  q[0] = i00 - 1.0f; q[1]  = i01;        q[2]  = i02;
  q[3] = -(i00 * t0 + i01 * t1 + i02 * t2);
  q[4] = i10;        q[5]  = i11 - 1.0f; q[6]  = i12;
  q[7] = -(i10 * t0 + i11 * t1 + i12 * t2);
  q[8] = i20;        q[9]  = i21;        q[10] = i22 - 1.0f;
  q[11] = -(i20 * t0 + i21 * t1 + i22 * t2);
}

__global__ __launch_bounds__(256) void invert_affine_kernel(
    const float4* __restrict__ in, float4* __restrict__ out, int nTiles, int B) {
  __shared__ float lds[TILE * PAD];
  const int t = threadIdx.x;

  // Per-k (s, r) and LDS offsets are tile-invariant: hoist.
  int off[3];
#pragma unroll
  for (int k = 0; k < 3; ++k) {
    const int j = k * TILE + t;
    const int s = j / 3, r = j - 3 * s;
    off[k] = PAD * s + 4 * r;
  }

  for (int tile = blockIdx.x; tile < nTiles; tile += gridDim.x) {
    const long base = (long)tile * (TILE * 3);  // float4 index of tile start

    // Phase A: coalesced global load -> padded LDS
#pragma unroll
    for (int k = 0; k < 3; ++k) {
      const float4 v = in[base + k * TILE + t];
      float* p = &lds[off[k]];
      p[0] = v.x; p[1] = v.y; p[2] = v.z; p[3] = v.w;
    }
    __syncthreads();

    // Phase B: invert own sample in place
    invert12(&lds[PAD * t], &lds[PAD * t]);
    __syncthreads();

    // Phase C: padded LDS -> coalesced global store
#pragma unroll
    for (int k = 0; k < 3; ++k) {
      const float* p = &lds[off[k]];
      out[base + k * TILE + t] = make_float4(p[0], p[1], p[2], p[3]);
    }
    __syncthreads();  // lds reused by next tile's phase A
  }

  // Tail (B not a multiple of TILE): direct strided path, rarely taken.
  const int tailStart = nTiles * TILE;
  for (int i = tailStart + blockIdx.x * (int)blockDim.x + t; i < B;
       i += gridDim.x * blockDim.x) {
    float buf[12], res[12];
    const float4 r0 = in[3 * (long)i + 0];
    const float4 r1 = in[3 * (long)i + 1];
    const float4 r2 = in[3 * (long)i + 2];
    buf[0] = r0.x; buf[1] = r0.y; buf[2]  = r0.z; buf[3]  = r0.w;
    buf[4] = r1.x; buf[5] = r1.y; buf[6]  = r1.z; buf[7]  = r1.w;
    buf[8] = r2.x; buf[9] = r2.y; buf[10] = r2.z; buf[11] = r2.w;
    invert12(buf, res);
    out[3 * (long)i + 0] = make_float4(res[0], res[1], res[2], res[3]);
    out[3 * (long)i + 1] = make_float4(res[4], res[5], res[6], res[7]);
    out[3 * (long)i + 2] = make_float4(res[8], res[9], res[10], res[11]);
  }
}

extern "C" void kernel_launch(void* const* d_in, const int* in_sizes, int n_in,
                              void* d_out, int out_size, void* d_ws, size_t ws_size,
                              hipStream_t stream) {
  (void)n_in; (void)d_ws; (void)ws_size; (void)out_size;
  const float4* in4 = (const float4*)d_in[0];
  float4* out4 = (float4*)d_out;
  const int B = in_sizes[0] / 12;  // samples
  const int nTiles = B / TILE;

  int blocks = nTiles > 0 ? nTiles : 1;
  if (blocks > 2048) blocks = 2048;  // 8 blocks/CU; grid-stride the rest

  invert_affine_kernel<<<blocks, 256, 0, stream>>>(in4, out4, nTiles, B);
}

// Round 3
// 79.367 us; speedup vs baseline: 1.1552x; 1.0055x over previous
//
#include <hip/hip_runtime.h>

// InvertAffine: per sample, trf (12 floats) -> rows of a 3x4 "shift" matrix.
// full = [[A+I, t],[0,1]]; inv(full) = [[Minv, -Minv*t],[0,1]] with M = A+I.
// out = [Minv - I | -Minv*t] flattened (12 floats).
//
// Wave-local staging: each wave transposes its own 64-sample chunk through a
// private LDS region, so NO __syncthreads() is needed (DS ops from a wave
// complete in order; __builtin_amdgcn_wave_barrier() stops compiler
// reordering). This removes the s_waitcnt vmcnt(0) drains that __syncthreads
// implies -- global loads/stores stay in flight across tile iterations.
//
// LDS PAD=13 dwords/sample: odd stride => 13*l mod 32 covers each bank exactly
// twice across 64 lanes (2-way aliasing is free on CDNA4).

#define PAD 13
#define TILE 256           // samples per block tile (== blockDim.x)
#define WSAMP 64           // samples per wave

__device__ __forceinline__ void invert12(const float* __restrict__ p,
                                         float* __restrict__ q) {
  const float a00 = p[0] + 1.0f, a01 = p[1],        a02 = p[2],         t0 = p[3];
  const float a10 = p[4],        a11 = p[5] + 1.0f, a12 = p[6],         t1 = p[7];
  const float a20 = p[8],        a21 = p[9],        a22 = p[10] + 1.0f, t2 = p[11];

  const float c00 = a11 * a22 - a12 * a21;
  const float c01 = a12 * a20 - a10 * a22;
  const float c02 = a10 * a21 - a11 * a20;

  const float det  = a00 * c00 + a01 * c01 + a02 * c02;
  const float rdet = 1.0f / det;

  const float i00 = c00 * rdet;
  const float i01 = (a02 * a21 - a01 * a22) * rdet;
  const float i02 = (a01 * a12 - a02 * a11) * rdet;
  const float i10 = c01 * rdet;
  const float i11 = (a00 * a22 - a02 * a20) * rdet;
  const float i12 = (a02 * a10 - a00 * a12) * rdet;
  const float i20 = c02 * rdet;
  const float i21 = (a01 * a20 - a00 * a21) * rdet;
  const float i22 = (a00 * a11 - a01 * a10) * rdet;

  q[0] = i00 - 1.0f; q[1]  = i01;        q[2]  = i02;
  q[3] = -(i00 * t0 + i01 * t1 + i02 * t2);
  q[4] = i10;        q[5]  = i11 - 1.0f; q[6]  = i12;
  q[7] = -(i10 * t0 + i11 * t1 + i12 * t2);
  q[8] = i20;        q[9]  = i21;        q[10] = i22 - 1.0f;
  q[11] = -(i20 * t0 + i21 * t1 + i22 * t2);
}

__global__ __launch_bounds__(256) void invert_affine_kernel(
    const float4* __restrict__ in, float4* __restrict__ out, int nTiles, int B) {
  __shared__ float lds[(TILE / WSAMP) * WSAMP * PAD];
  const int t = threadIdx.x;
  const int w = t >> 6;   // wave id within block
  const int l = t & 63;   // lane id
  float* __restrict__ wlds = &lds[w * (WSAMP * PAD)];

  // Transposed LDS offsets for this lane's 3 float4 slots (tile-invariant).
  int off[3];
#pragma unroll
  for (int k = 0; k < 3; ++k) {
    const int j = k * WSAMP + l;          // float4 index within wave chunk
    const int s = j / 3, r = j - 3 * s;   // sample, row
    off[k] = PAD * s + 4 * r;
  }

  for (int tile = blockIdx.x; tile < nTiles; tile += gridDim.x) {
    // float4 index of this wave's 64-sample chunk (192 contiguous float4s)
    const long long base = (long long)tile * (TILE * 3) + w * (WSAMP * 3);

    // Phase A: coalesced global load -> transposed write into wave-private LDS
#pragma unroll
    for (int k = 0; k < 3; ++k) {
      const float4 v = in[base + k * WSAMP + l];
      float* p = &wlds[off[k]];
      p[0] = v.x; p[1] = v.y; p[2] = v.z; p[3] = v.w;
    }
    __builtin_amdgcn_wave_barrier();   // keep DS write<->read order (in-order per wave)

    // Phase B: invert own sample (reads other lanes' writes), results to regs
    float res[12];
    invert12(&wlds[PAD * l], res);
    __builtin_amdgcn_wave_barrier();

    // write results back transposed
#pragma unroll
    for (int c = 0; c < 12; ++c) wlds[PAD * l + c] = res[c];
    __builtin_amdgcn_wave_barrier();

    // Phase C: LDS -> coalesced global store
#pragma unroll
    for (int k = 0; k < 3; ++k) {
      const float* p = &wlds[off[k]];
      out[base + k * WSAMP + l] = make_float4(p[0], p[1], p[2], p[3]);
    }
    __builtin_amdgcn_wave_barrier();   // next tile's phase A rewrites wlds
  }

  // Tail (B not a multiple of TILE): direct strided path, rarely taken.
  const int tailStart = nTiles * TILE;
  for (int i = tailStart + blockIdx.x * (int)blockDim.x + t; i < B;
       i += gridDim.x * blockDim.x) {
    float buf[12], res[12];
    const float4 r0 = in[3 * (long long)i + 0];
    const float4 r1 = in[3 * (long long)i + 1];
    const float4 r2 = in[3 * (long long)i + 2];
    buf[0] = r0.x; buf[1] = r0.y; buf[2]  = r0.z; buf[3]  = r0.w;
    buf[4] = r1.x; buf[5] = r1.y; buf[6]  = r1.z; buf[7]  = r1.w;
    buf[8] = r2.x; buf[9] = r2.y; buf[10] = r2.z; buf[11] = r2.w;
    invert12(buf, res);
    out[3 * (long long)i + 0] = make_float4(res[0], res[1], res[2], res[3]);
    out[3 * (long long)i + 1] = make_float4(res[4], res[5], res[6], res[7]);
    out[3 * (long long)i + 2] = make_float4(res[8], res[9], res[10], res[11]);
  }
}

extern "C" void kernel_launch(void* const* d_in, const int* in_sizes, int n_in,
                              void* d_out, int out_size, void* d_ws, size_t ws_size,
                              hipStream_t stream) {
  (void)n_in; (void)d_ws; (void)ws_size; (void)out_size;
  const float4* in4 = (const float4*)d_in[0];
  float4* out4 = (float4*)d_out;
  const int B = in_sizes[0] / 12;  // samples
  const int nTiles = B / TILE;

  int blocks = nTiles > 0 ? nTiles : 1;
  if (blocks > 2048) blocks = 2048;  // 8 blocks/CU; grid-stride the rest

  invert_affine_kernel<<<blocks, 256, 0, stream>>>(in4, out4, nTiles, B);
}

// Round 5
// 77.370 us; speedup vs baseline: 1.1851x; 1.0258x over previous
//
#include <hip/hip_runtime.h>

// InvertAffine: per sample, trf (12 floats) -> rows of a 3x4 "shift" matrix.
// full = [[A+I, t],[0,1]]; inv(full) = [[Minv, -Minv*t],[0,1]] with M = A+I.
// out = [Minv - I | -Minv*t] flattened (12 floats).
//
// Structure:
//  - Wave-local LDS transpose (64 samples/wave, PAD=13 => 2-way bank alias, free).
//  - Depth-1 software pipeline: next tile's 3 global loads are issued before
//    processing the current tile, so each wave keeps loads in flight through
//    the LDS/compute phases (copy-kernel-style memory issue continuity).
//  - Nontemporal loads/stores: data touched exactly once, skip cache alloc.
//    NOTE: __builtin_nontemporal_* requires a TRUE vector type (ext_vector),
//    not HIP_vector_type<float,4> -- hence f4 below.

typedef float f4 __attribute__((ext_vector_type(4)));

#define PAD 13
#define TILE 256           // samples per block tile (== blockDim.x)
#define WSAMP 64           // samples per wave

__device__ __forceinline__ void invert12(const float* __restrict__ p,
                                         float* __restrict__ q) {
  const float a00 = p[0] + 1.0f, a01 = p[1],        a02 = p[2],         t0 = p[3];
  const float a10 = p[4],        a11 = p[5] + 1.0f, a12 = p[6],         t1 = p[7];
  const float a20 = p[8],        a21 = p[9],        a22 = p[10] + 1.0f, t2 = p[11];

  const float c00 = a11 * a22 - a12 * a21;
  const float c01 = a12 * a20 - a10 * a22;
  const float c02 = a10 * a21 - a11 * a20;

  const float det  = a00 * c00 + a01 * c01 + a02 * c02;
  const float rdet = 1.0f / det;

  const float i00 = c00 * rdet;
  const float i01 = (a02 * a21 - a01 * a22) * rdet;
  const float i02 = (a01 * a12 - a02 * a11) * rdet;
  const float i10 = c01 * rdet;
  const float i11 = (a00 * a22 - a02 * a20) * rdet;
  const float i12 = (a02 * a10 - a00 * a12) * rdet;
  const float i20 = c02 * rdet;
  const float i21 = (a01 * a20 - a00 * a21) * rdet;
  const float i22 = (a00 * a11 - a01 * a10) * rdet;

  q[0] = i00 - 1.0f; q[1]  = i01;        q[2]  = i02;
  q[3] = -(i00 * t0 + i01 * t1 + i02 * t2);
  q[4] = i10;        q[5]  = i11 - 1.0f; q[6]  = i12;
  q[7] = -(i10 * t0 + i11 * t1 + i12 * t2);
  q[8] = i20;        q[9]  = i21;        q[10] = i22 - 1.0f;
  q[11] = -(i20 * t0 + i21 * t1 + i22 * t2);
}

__global__ __launch_bounds__(256) void invert_affine_kernel(
    const f4* __restrict__ in, f4* __restrict__ out,
    int nTiles, int B, int per) {
  __shared__ float lds[(TILE / WSAMP) * WSAMP * PAD];
  const int t = threadIdx.x;
  const int w = t >> 6;   // wave id within block
  const int l = t & 63;   // lane id
  float* __restrict__ wlds = &lds[w * (WSAMP * PAD)];

  // Transposed LDS offsets for this lane's 3 float4 slots (tile-invariant).
  int off[3];
#pragma unroll
  for (int k = 0; k < 3; ++k) {
    const int j = k * WSAMP + l;          // float4 index within wave chunk
    const int s = j / 3, r = j - 3 * s;   // sample, row
    off[k] = PAD * s + 4 * r;
  }

  const int tileBeg = blockIdx.x * per;
  const int tileEnd = (tileBeg + per < nTiles) ? tileBeg + per : nTiles;

  if (tileBeg < tileEnd) {
    // float4 index of this wave's chunk within the first tile
    long long base = (long long)tileBeg * (TILE * 3) + w * (WSAMP * 3);

    // Prologue: load first tile
    f4 cur0 = __builtin_nontemporal_load(&in[base + 0 * WSAMP + l]);
    f4 cur1 = __builtin_nontemporal_load(&in[base + 1 * WSAMP + l]);
    f4 cur2 = __builtin_nontemporal_load(&in[base + 2 * WSAMP + l]);

    for (int tile = tileBeg; tile < tileEnd; ++tile) {
      // Issue next tile's loads FIRST -- they stay in flight through the
      // whole LDS/compute/store body below.
      f4 nxt0, nxt1, nxt2;
      const bool more = (tile + 1) < tileEnd;
      if (more) {
        const long long nb = base + (TILE * 3);
        nxt0 = __builtin_nontemporal_load(&in[nb + 0 * WSAMP + l]);
        nxt1 = __builtin_nontemporal_load(&in[nb + 1 * WSAMP + l]);
        nxt2 = __builtin_nontemporal_load(&in[nb + 2 * WSAMP + l]);
      }

      // Phase A: transposed write of current tile into wave-private LDS
      {
        float* p0 = &wlds[off[0]];
        p0[0] = cur0.x; p0[1] = cur0.y; p0[2] = cur0.z; p0[3] = cur0.w;
        float* p1 = &wlds[off[1]];
        p1[0] = cur1.x; p1[1] = cur1.y; p1[2] = cur1.z; p1[3] = cur1.w;
        float* p2 = &wlds[off[2]];
        p2[0] = cur2.x; p2[1] = cur2.y; p2[2] = cur2.z; p2[3] = cur2.w;
      }
      __builtin_amdgcn_wave_barrier();  // cross-lane LDS write->read ordering

      // Phase B: invert own sample, write results back in place
      float res[12];
      invert12(&wlds[PAD * l], res);
#pragma unroll
      for (int c = 0; c < 12; ++c) wlds[PAD * l + c] = res[c];
      __builtin_amdgcn_wave_barrier();  // cross-lane LDS write->read ordering

      // Phase C: LDS -> coalesced nontemporal global store
#pragma unroll
      for (int k = 0; k < 3; ++k) {
        const float* p = &wlds[off[k]];
        f4 v; v.x = p[0]; v.y = p[1]; v.z = p[2]; v.w = p[3];
        __builtin_nontemporal_store(v, &out[base + k * WSAMP + l]);
      }
      __builtin_amdgcn_wave_barrier();  // next iter's phase A rewrites wlds

      cur0 = nxt0; cur1 = nxt1; cur2 = nxt2;
      base += TILE * 3;
    }
  }

  // Tail (B not a multiple of TILE): direct strided path, rarely taken.
  const int tailStart = nTiles * TILE;
  for (int i = tailStart + blockIdx.x * (int)blockDim.x + t; i < B;
       i += gridDim.x * blockDim.x) {
    float buf[12], res[12];
    const f4 r0 = in[3 * (long long)i + 0];
    const f4 r1 = in[3 * (long long)i + 1];
    const f4 r2 = in[3 * (long long)i + 2];
    buf[0] = r0.x; buf[1] = r0.y; buf[2]  = r0.z; buf[3]  = r0.w;
    buf[4] = r1.x; buf[5] = r1.y; buf[6]  = r1.z; buf[7]  = r1.w;
    buf[8] = r2.x; buf[9] = r2.y; buf[10] = r2.z; buf[11] = r2.w;
    invert12(buf, res);
    f4 o0; o0.x = res[0]; o0.y = res[1];  o0.z = res[2];  o0.w = res[3];
    f4 o1; o1.x = res[4]; o1.y = res[5];  o1.z = res[6];  o1.w = res[7];
    f4 o2; o2.x = res[8]; o2.y = res[9];  o2.z = res[10]; o2.w = res[11];
    out[3 * (long long)i + 0] = o0;
    out[3 * (long long)i + 1] = o1;
    out[3 * (long long)i + 2] = o2;
  }
}

extern "C" void kernel_launch(void* const* d_in, const int* in_sizes, int n_in,
                              void* d_out, int out_size, void* d_ws, size_t ws_size,
                              hipStream_t stream) {
  (void)n_in; (void)d_ws; (void)ws_size; (void)out_size;
  const f4* in4 = (const f4*)d_in[0];
  f4* out4 = (f4*)d_out;
  const int B = in_sizes[0] / 12;  // samples
  const int nTiles = B / TILE;

  int blocks = nTiles > 0 ? nTiles : 1;
  if (blocks > 2048) blocks = 2048;  // fully-resident grid (8 blocks/CU)
  const int per = (nTiles + blocks - 1) / blocks;  // contiguous tiles per block

  invert_affine_kernel<<<blocks, 256, 0, stream>>>(in4, out4, nTiles, B, per);
}